// Round 10
// baseline (380.622 us; speedup 1.0000x reference)
//
#include <hip/hip_runtime.h>
#include <stdint.h>

#define D_IN 128
#define D_OUT 128
#define NREL 8
#define NBASE 4
#define ELLCAP 64

typedef __attribute__((ext_vector_type(8))) short short8;
typedef __attribute__((ext_vector_type(4))) float floatx4;

__device__ __forceinline__ unsigned short f2bf(float f) {
  unsigned int u = __float_as_uint(f);
  u += 0x7fffu + ((u >> 16) & 1u);
  return (unsigned short)(u >> 16);
}
__device__ __forceinline__ unsigned pack2bf(float lo, float hi) {
  return (unsigned)f2bf(lo) | ((unsigned)f2bf(hi) << 16);
}
__device__ __forceinline__ float bflo(unsigned int u) { return __uint_as_float(u << 16); }
__device__ __forceinline__ float bfhi(unsigned int u) { return __uint_as_float(u & 0xffff0000u); }

// ---------- 1) prep: cast X fp32->bf16 + build W2T + zero cursor ----------
// W2T[o][c] = w_bases[b][k][o], c = k*4+b  (bf16, [128][512])
__global__ void k_prep(const float4* __restrict__ X, ushort4* __restrict__ Xb, int n4,
                       const float* __restrict__ w_bases, unsigned short* __restrict__ W2T,
                       uint4* __restrict__ cursor4, int nc4) {
  int i = blockIdx.x * blockDim.x + threadIdx.x;
  if (i < n4) {
    float4 v = X[i];
    ushort4 o;
    o.x = f2bf(v.x); o.y = f2bf(v.y); o.z = f2bf(v.z); o.w = f2bf(v.w);
    Xb[i] = o;
  }
  if (i < 128 * 512) {
    int o = i >> 9, c = i & 511;
    int k = c >> 2, b = c & 3;
    W2T[i] = f2bf(w_bases[(b * D_IN + k) * D_OUT + o]);
  }
  if (i < nc4) cursor4[i] = make_uint4(0u, 0u, 0u, 0u);
}

// ---------- 2) fill padded ELL; cursor[d] ends as degree ----------
__global__ void k_fill(const int* __restrict__ src, const int* __restrict__ dst,
                       const int* __restrict__ rel, const float* __restrict__ val,
                       int* __restrict__ cursor, uint2* __restrict__ ell, int E) {
  int i = blockIdx.x * blockDim.x + threadIdx.x;
  if (i >= E) return;
  int d = dst[i];
  int pos = atomicAdd(&cursor[d], 1);
  if (pos < ELLCAP)
    ell[(size_t)d * ELLCAP + pos] =
        make_uint2((unsigned)src[i] | ((unsigned)rel[i] << 21), __float_as_uint(val[i]));
}

// ---------- 3) fused agg + MFMA, 16-lane-group gather ----------
// Block = 4 waves (256 thr), 16 dst rows. Each wave: 4 groups of 16 lanes,
// group g handles row wave*4+g; lane s loads uint4 = 16B of the src row
// (features 8s..8s+7). Metadata for 16 edges loaded in one instruction and
// __shfl-distributed. 4-edge unroll -> 4 KB in flight per wave.
__global__ __launch_bounds__(256, 4)
void k_agg16(const uint2* __restrict__ ell, const int* __restrict__ cursor,
             const float* __restrict__ w_rel_g, const uint4* __restrict__ Xb4,
             const unsigned short* __restrict__ W2T, float* __restrict__ out, int Nn) {
  __shared__ unsigned short aggS[16][520];
  __shared__ float wr[NREL * NBASE];
  if (threadIdx.x < NREL * NBASE) wr[threadIdx.x] = w_rel_g[threadIdx.x];
  __syncthreads();

  const int tid = threadIdx.x;
  const int wave = tid >> 6, lane = tid & 63;
  const int g = lane >> 4, s = lane & 15, gb = lane & 48;
  const int dstb = blockIdx.x * 16;
  const int lrow = wave * 4 + g;
  const int dst = dstb + lrow;

  float acc[NBASE][8];
#pragma unroll
  for (int b = 0; b < NBASE; ++b)
#pragma unroll
    for (int f = 0; f < 8; ++f) acc[b][f] = 0.f;

  int deg = 0;
  if (dst < Nn) {
    int c = cursor[dst];
    deg = c < ELLCAP ? c : ELLCAP;
  }
  const uint2* eb = ell + (size_t)dst * ELLCAP;

  auto fmae = [&](unsigned mx, unsigned my, uint4 y) {
    float val = __uint_as_float(my);
    const float* w = &wr[((mx >> 21) & 7u) * 4];
    float c0 = val * w[0], c1 = val * w[1], c2 = val * w[2], c3 = val * w[3];
#pragma unroll
    for (int p = 0; p < 4; ++p) {
      unsigned u = (&y.x)[p];
      float xl = bflo(u), xh = bfhi(u);
      acc[0][2 * p] += c0 * xl; acc[1][2 * p] += c1 * xl;
      acc[2][2 * p] += c2 * xl; acc[3][2 * p] += c3 * xl;
      acc[0][2 * p + 1] += c0 * xh; acc[1][2 * p + 1] += c1 * xh;
      acc[2][2 * p + 1] += c2 * xh; acc[3][2 * p + 1] += c3 * xh;
    }
  };

  for (int base0 = 0; base0 < deg; base0 += 16) {
    const int chunk = (deg - base0) < 16 ? (deg - base0) : 16;
    uint2 mm = make_uint2(0u, 0u);
    if (s < chunk) mm = eb[base0 + s];  // 16 edges' metadata, one load
    int j = 0;
    for (; j + 4 <= chunk; j += 4) {  // 4 KB in flight per wave
      unsigned mx0 = __shfl(mm.x, gb + j),     my0 = __shfl(mm.y, gb + j);
      unsigned mx1 = __shfl(mm.x, gb + j + 1), my1 = __shfl(mm.y, gb + j + 1);
      unsigned mx2 = __shfl(mm.x, gb + j + 2), my2 = __shfl(mm.y, gb + j + 2);
      unsigned mx3 = __shfl(mm.x, gb + j + 3), my3 = __shfl(mm.y, gb + j + 3);
      uint4 y0 = Xb4[(size_t)(mx0 & 0x1FFFFFu) * 16 + s];
      uint4 y1 = Xb4[(size_t)(mx1 & 0x1FFFFFu) * 16 + s];
      uint4 y2 = Xb4[(size_t)(mx2 & 0x1FFFFFu) * 16 + s];
      uint4 y3 = Xb4[(size_t)(mx3 & 0x1FFFFFu) * 16 + s];
      fmae(mx0, my0, y0); fmae(mx1, my1, y1);
      fmae(mx2, my2, y2); fmae(mx3, my3, y3);
    }
    for (; j + 2 <= chunk; j += 2) {
      unsigned mx0 = __shfl(mm.x, gb + j),     my0 = __shfl(mm.y, gb + j);
      unsigned mx1 = __shfl(mm.x, gb + j + 1), my1 = __shfl(mm.y, gb + j + 1);
      uint4 y0 = Xb4[(size_t)(mx0 & 0x1FFFFFu) * 16 + s];
      uint4 y1 = Xb4[(size_t)(mx1 & 0x1FFFFFu) * 16 + s];
      fmae(mx0, my0, y0); fmae(mx1, my1, y1);
    }
    for (; j < chunk; ++j) {
      unsigned mx0 = __shfl(mm.x, gb + j), my0 = __shfl(mm.y, gb + j);
      uint4 y0 = Xb4[(size_t)(mx0 & 0x1FFFFFu) * 16 + s];
      fmae(mx0, my0, y0);
    }
  }

  // store: c = 4k+b, k = 8s+f  ->  aggS[lrow][32s + 4f + b]; 64 B/lane
#pragma unroll
  for (int f2 = 0; f2 < 4; ++f2) {
    uint4 o;
    o.x = pack2bf(acc[0][2 * f2],     acc[1][2 * f2]);
    o.y = pack2bf(acc[2][2 * f2],     acc[3][2 * f2]);
    o.z = pack2bf(acc[0][2 * f2 + 1], acc[1][2 * f2 + 1]);
    o.w = pack2bf(acc[2][2 * f2 + 1], acc[3][2 * f2 + 1]);
    *(uint4*)&aggS[lrow][32 * s + 8 * f2] = o;
  }
  __syncthreads();

  // phase 2: 16x512 @ 512x128; wave covers cols wave*32..+31
  const int q = lane >> 4, r16 = lane & 15;
  const int jb = wave * 32;
  const floatx4 zero = {0.f, 0.f, 0.f, 0.f};
  floatx4 a0 = zero, a1 = zero;
#pragma unroll 4
  for (int k0 = 0; k0 < 512; k0 += 32) {
    int ka = k0 + q * 8;
    short8 af = *(const short8*)&aggS[r16][ka];
    short8 bf0 = *(const short8*)(W2T + (size_t)(jb + r16) * 512 + ka);
    short8 bf1 = *(const short8*)(W2T + (size_t)(jb + 16 + r16) * 512 + ka);
    a0 = __builtin_amdgcn_mfma_f32_16x16x32_bf16(af, bf0, a0, 0, 0, 0);
    a1 = __builtin_amdgcn_mfma_f32_16x16x32_bf16(af, bf1, a1, 0, 0, 0);
  }
  // C/D layout col=lane&15, row=(lane>>4)*4+p  [m89/m91-verified]
#pragma unroll
  for (int p = 0; p < 4; ++p) {
    int grow = dstb + q * 4 + p;
    if (grow < Nn) {
      out[(size_t)grow * 128 + jb + r16] = a0[p];
      out[(size_t)grow * 128 + jb + 16 + r16] = a1[p];
    }
  }
}

extern "C" void kernel_launch(void* const* d_in, const int* in_sizes, int n_in,
                              void* d_out, int out_size, void* d_ws, size_t ws_size,
                              hipStream_t stream) {
  const float* X = (const float*)d_in[0];
  const int* esrc = (const int*)d_in[1];
  const int* edst = (const int*)d_in[2];
  const int* erel = (const int*)d_in[3];
  const float* eval_ = (const float*)d_in[4];
  const float* w_bases = (const float*)d_in[5];
  const float* w_rel = (const float*)d_in[6];
  const int Nn = in_sizes[0] / D_IN;  // 100000
  const int E = in_sizes[1];          // 640000

  char* ws = (char*)d_ws;
  size_t off = 0;
  auto alloc = [&](size_t bytes) -> char* {
    char* p = ws + off;
    off += (bytes + 255) & ~(size_t)255;
    return p;
  };
  unsigned short* Xb = (unsigned short*)alloc((size_t)Nn * D_IN * 2);       // 25.6 MB
  unsigned short* W2T = (unsigned short*)alloc((size_t)128 * 512 * 2);      // 128 KB
  int* cursor = (int*)alloc((size_t)((Nn + 3) & ~3) * 4);                   // 0.4 MB
  uint2* ell = (uint2*)alloc((size_t)Nn * ELLCAP * 8);                      // 51.2 MB
  (void)ws_size;

  int n4 = Nn * D_IN / 4;  // 3.2M
  int nc4 = (Nn + 3) / 4;
  k_prep<<<(n4 + 255) / 256, 256, 0, stream>>>((const float4*)X, (ushort4*)Xb, n4,
                                               w_bases, W2T, (uint4*)cursor, nc4);

  k_fill<<<(E + 255) / 256, 256, 0, stream>>>(esrc, edst, erel, eval_, cursor, ell, E);

  k_agg16<<<(Nn + 15) / 16, 256, 0, stream>>>(ell, cursor, w_rel,
                                              (const uint4*)Xb, W2T,
                                              (float*)d_out, Nn);
}